// Round 11
// baseline (152.867 us; speedup 1.0000x reference)
//
#include <hip/hip_runtime.h>

// ---------------------------------------------------------------------------
// EnhancedBlockGabor on MI355X (gfx950) — R11 = R10 + border-addressing fix
//   prep     : filters -> A bf16 [48][256]; w1 -> bf16 [32][32][32]; zero stats
//   conv_mix : per (b,h) block, 32 channels, barrier-free, wave-private LDS.
//              Staging reads x (f32) directly with PER-ELEMENT predicated
//              addressing (R10 clamped the base offset while masking the
//              unclamped position -> border pixels read shifted neighbors,
//              absmax 1.25). Inline f32->bf16, writes both phase replicas.
//              Rotated s-pipeline + deferred mix + fused stats (R8 body).
//   inorm2   : normalize + H<->W transpose via 32x32 LDS tiles
// b1 ignored: per-channel constant cancels under instance norm.
// ---------------------------------------------------------------------------

typedef __attribute__((ext_vector_type(8))) short bfx8;
typedef __attribute__((ext_vector_type(4))) float fx4;
typedef __attribute__((ext_vector_type(4))) unsigned ux4;
typedef __attribute__((ext_vector_type(2))) unsigned ux2;

#define A_OFF    ((size_t)0)
#define W1B_OFF  (A_OFF + (size_t)48 * 256 * 2)
#define YP_OFF   (W1B_OFF + (size_t)32 * 32 * 32 * 2)
#define ST_OFF   (YP_OFF + (size_t)128 * 16384 * 4)
// total ws: ~8.5 MiB

// wave-private staging (dwords): row stride 40 (==8 mod 32), rep stride 656
// (==16 mod 32) -> all fragment reads exactly 2-way banked (free, m136).
#define WROW_DW  40
#define WREP_DW  656
#define WBUF_DW  (2 * WREP_DW)             // 1312 dw per buffer
#define WWAVE_DW (2 * WBUF_DW)             // 2624 dw per wave (two buffers)

__device__ __forceinline__ unsigned short f2bf(float f) {
    unsigned u = __float_as_uint(f);
    u = (u + 0x7FFFu + ((u >> 16) & 1u)) >> 16;   // RTNE
    return (unsigned short)u;
}

// cheap round-half-up pack of two floats to one bf16x2 dword
__device__ __forceinline__ unsigned pkbf(float a, float b) {
    unsigned ua = __float_as_uint(a) + 0x8000u;
    unsigned ub = __float_as_uint(b) + 0x8000u;
    return (ua >> 16) | (ub & 0xFFFF0000u);
}

__device__ __forceinline__ float fsqrt(float x) {
    float r;
    asm("v_sqrt_f32 %0, %1" : "=v"(r) : "v"(x));
    return r;
}

// ---- tiny prep: A + w1b + stats-zero -------------------------------------
__global__ void prep(const float* __restrict__ filt, const float* __restrict__ w1,
                     unsigned short* __restrict__ A, unsigned short* __restrict__ w1b,
                     float* __restrict__ stats)
{
    int t = blockIdx.x * 256 + threadIdx.x;
    if (t < 48 * 256) {
        int f = t >> 8, k = t & 255;
        int ky = k >> 4, kx = k & 15;
        float v = 0.f;
        if (ky < 15 && kx < 15) v = filt[(f * 15 + ky) * 15 + kx];
        A[t] = f2bf(v);
    } else if (t < 48 * 256 + 32 * 32 * 32) {
        int j = t - 48 * 256;
        int c = j >> 10, o = (j >> 5) & 31, so = j & 31;
        float v = (so < 24) ? w1[o * 768 + c * 24 + so] : 0.f;
        w1b[j] = f2bf(v);
    } else if (t < 48 * 256 + 32 * 32 * 32 + 256) {
        stats[t - (48 * 256 + 32 * 32 * 32)] = 0.f;
    }
}

// ---- fused conv + magnitude + channel-mix + stats ------------------------
// grid 512 = 4 b x 128 h, XCD-swizzled. 2 blocks/CU, one pass, no main-loop
// barriers (all LDS wave-private). Staging reads x f32 directly.
__global__ void __attribute__((amdgpu_waves_per_eu(2, 2)))
__launch_bounds__(256)
conv_mix(const float* __restrict__ x,
         const unsigned short* __restrict__ Aw,
         const unsigned short* __restrict__ w1b,
         float* __restrict__ ypart, float* __restrict__ stats)
{
    __shared__ __align__(16) unsigned stagew[4 * WWAVE_DW]; // 41,984 B
    __shared__ unsigned mag_lds[2][4][32][20];     // 20,480 B, double-buffered
    __shared__ float stat_lds[4][4][16];           // 1 KB

    const int tid  = threadIdx.x;
    const int lane = tid & 63;
    const int wave = tid >> 6;
    const int n    = lane & 15;                    // MFMA row(A) / col(B,D)
    const int q    = lane >> 4;                    // MFMA k-octet / D row group

    const int bid = blockIdx.x;                    // xcd = bid & 7
    const int b   = (bid >> 1) & 3;
    const int h   = (bid & 1) * 64 + (bid >> 3);

    if (lane < 32) {                               // zero so=24..31 pads
        ux4 z4 = {0u, 0u, 0u, 0u};
        *(ux4*)&mag_lds[0][wave][lane][12] = z4;
        *(ux4*)&mag_lds[1][wave][lane][12] = z4;
    }

    // A fragments pinned (land in AGPRs; MFMA reads A from AGPR on gfx950)
    ux4 afr[3][8];
#pragma unroll
    for (int mt = 0; mt < 3; ++mt)
#pragma unroll
        for (int s = 0; s < 8; ++s)
            afr[mt][s] = *(const ux4*)(Aw + ((mt * 16 + n) * 256 + s * 32 + q * 8));
#pragma unroll
    for (int mt = 0; mt < 3; ++mt)
#pragma unroll
        for (int s = 0; s < 8; ++s)
            asm volatile("" : "+v"(afr[mt][s]));

    const int px0 = wave * 32;
    const int p   = n & 1;                         // phase replica
    const int fbase = wave * WWAVE_DW + p * WREP_DW + (q >> 1) * WROW_DW
                    + ((n - p) >> 1) + (q & 1) * 4;

    // staging map: 192 slots = 16 rows x 12 groups of 4 shorts; 3 per lane.
    // slot writes rep0 shorts [4sl..4sl+3] = x_pad cols px0+4sl+0..3 and
    // rep1 shorts [4sl..4sl+3] = x_pad cols px0+4sl+1..4; needs f32 x at
    // image cols cc0..cc0+4, cc0 = px0+4sl-7, row rr = h+row-7.
    int s_off[3], l_rep0[3];
    unsigned s_msk[3];
#pragma unroll
    for (int i = 0; i < 3; ++i) {
        int slot = i * 64 + lane;
        int row  = slot / 12;
        int sl   = slot - row * 12;
        int rr   = h + row - 7;
        int cc0  = px0 + sl * 4 - 7;
        unsigned m = 0;
        if (rr >= 0 && rr < 128) {
#pragma unroll
            for (int k = 0; k < 5; ++k)
                if (cc0 + k >= 0 && cc0 + k < 128) m |= 1u << k;
        }
        s_msk[i] = m;
        s_off[i] = rr * 128 + cc0;                 // UNCLAMPED; predicated/elem
        l_rep0[i] = wave * WWAVE_DW + row * WROW_DW + sl * 2;
    }
    const float* xb0 = x + (size_t)(b * 32) * 16384;   // channel 0 image

    const fx4 zero4 = {0.f, 0.f, 0.f, 0.f};
    fx4 yacc[2][2];
#pragma unroll
    for (int mt = 0; mt < 2; ++mt)
#pragma unroll
        for (int t = 0; t < 2; ++t) yacc[mt][t] = zero4;

    // prologue: stage channel 0 into buf 0 (wave-private; no barrier)
    {
        const float* xi = xb0;
#pragma unroll
        for (int i = 0; i < 3; ++i) {
            float f[5];
#pragma unroll
            for (int k = 0; k < 5; ++k) {
                const bool v = (s_msk[i] >> k) & 1;
                const int idx = v ? s_off[i] + k : 0;   // always in-bounds
                float raw = xi[idx];
                f[k] = v ? raw : 0.f;
            }
            ux2 r0 = {pkbf(f[0], f[1]), pkbf(f[2], f[3])};
            ux2 r1 = {pkbf(f[1], f[2]), pkbf(f[3], f[4])};
            *(ux2*)&stagew[l_rep0[i]] = r0;
            *(ux2*)&stagew[l_rep0[i] + WREP_DW] = r1;
        }
    }

    bfx8 wfp[2];                                   // w1 frags for channel c-1

    for (int c = 0; c < 32; ++c) {
        // 1) issue next channel's x loads (land during compute)
        float nf[3][5];
        if (c < 31) {
            const float* xi = xb0 + (size_t)(c + 1) * 16384;
#pragma unroll
            for (int i = 0; i < 3; ++i)
#pragma unroll
                for (int k = 0; k < 5; ++k) {
                    const bool v = (s_msk[i] >> k) & 1;
                    const int idx = v ? s_off[i] + k : 0;
                    float raw = xi[idx];
                    nf[i][k] = v ? raw : 0.f;
                }
        }

        // 2) read previous channel's magnitudes (written a full iter ago)
        ux4 magp[2];
        if (c > 0) {
            const int pbuf = (c & 1) ^ 1;
#pragma unroll
            for (int t = 0; t < 2; ++t)
                magp[t] = *(const ux4*)&mag_lds[pbuf][wave][t * 16 + n][q * 4];
        }

        // 3) w1 fragments for channel c (used next iteration)
        bfx8 wfc[2];
#pragma unroll
        for (int mt = 0; mt < 2; ++mt)
            wfc[mt] = *(const bfx8*)(w1b + ((c * 32 + mt * 16 + n) * 32 + q * 8));

        // 4) rotated s-pipeline: preload frags s+1 while MFMAs of s issue
        const int fb = fbase + (c & 1) * WBUF_DW;
        ux4 braw[2][2];                            // [s parity][t]
#pragma unroll
        for (int t = 0; t < 2; ++t) {
            const int ix = fb + t * 8;
            ux4 v = {stagew[ix], stagew[ix + 1], stagew[ix + 2], stagew[ix + 3]};
            braw[0][t] = v;
        }

        fx4 cacc[3][2];
#pragma unroll
        for (int mt = 0; mt < 3; ++mt)
#pragma unroll
            for (int t = 0; t < 2; ++t) cacc[mt][t] = zero4;

#pragma unroll
        for (int s = 0; s < 8; ++s) {
            if (s < 7) {
#pragma unroll
                for (int t = 0; t < 2; ++t) {
                    const int ix = fb + (s + 1) * (2 * WROW_DW) + t * 8;
                    ux4 v = {stagew[ix], stagew[ix + 1],
                             stagew[ix + 2], stagew[ix + 3]};
                    braw[(s + 1) & 1][t] = v;
                }
            }
#pragma unroll
            for (int t = 0; t < 2; ++t) {
                bfx8 bf = __builtin_bit_cast(bfx8, braw[s & 1][t]);
#pragma unroll
                for (int mt = 0; mt < 3; ++mt)
                    cacc[mt][t] = __builtin_amdgcn_mfma_f32_16x16x32_bf16(
                        __builtin_bit_cast(bfx8, afr[mt][s]), bf, cacc[mt][t], 0, 0, 0);
            }
            if (s == 1 && c > 0) {                 // deferred mix for c-1
#pragma unroll
                for (int t = 0; t < 2; ++t) {
                    bfx8 mb = __builtin_bit_cast(bfx8, magp[t]);
#pragma unroll
                    for (int mt = 0; mt < 2; ++mt)
                        yacc[mt][t] = __builtin_amdgcn_mfma_f32_16x16x32_bf16(
                            wfp[mt], mb, yacc[mt][t], 0, 0, 0);
                }
            }
        }

        // 5) magnitudes -> mag buffer (c&1); consumed next iteration
#pragma unroll
        for (int t = 0; t < 2; ++t)
#pragma unroll
            for (int mt = 0; mt < 3; ++mt) {
                float m0 = fsqrt(cacc[mt][t][0] * cacc[mt][t][0] +
                                 cacc[mt][t][1] * cacc[mt][t][1]);
                float m1 = fsqrt(cacc[mt][t][2] * cacc[mt][t][2] +
                                 cacc[mt][t][3] * cacc[mt][t][3]);
                mag_lds[c & 1][wave][t * 16 + n][4 * mt + q] = pkbf(m0, m1);
            }

        // 6) convert + write next channel's staging (both replicas, no sync)
        if (c < 31) {
            const int wb = ((c + 1) & 1) * WBUF_DW;
#pragma unroll
            for (int i = 0; i < 3; ++i) {
                ux2 r0 = {pkbf(nf[i][0], nf[i][1]), pkbf(nf[i][2], nf[i][3])};
                ux2 r1 = {pkbf(nf[i][1], nf[i][2]), pkbf(nf[i][3], nf[i][4])};
                *(ux2*)&stagew[wb + l_rep0[i]] = r0;
                *(ux2*)&stagew[wb + l_rep0[i] + WREP_DW] = r1;
            }
        }
#pragma unroll
        for (int mt = 0; mt < 2; ++mt) wfp[mt] = wfc[mt];
    }

    // final deferred mix (channel 31, buffer 1)
#pragma unroll
    for (int t = 0; t < 2; ++t) {
        ux4 raw = *(const ux4*)&mag_lds[1][wave][t * 16 + n][q * 4];
        bfx8 mb = __builtin_bit_cast(bfx8, raw);
#pragma unroll
        for (int mt = 0; mt < 2; ++mt)
            yacc[mt][t] = __builtin_amdgcn_mfma_f32_16x16x32_bf16(
                wfp[mt], mb, yacc[mt][t], 0, 0, 0);
    }

    // ---- epilogue: y store + fused instance-norm partial stats ----------
    float* yp = ypart + (size_t)(b * 32) * 16384 + h * 128;
#pragma unroll
    for (int mt = 0; mt < 2; ++mt)
#pragma unroll
        for (int t = 0; t < 2; ++t) {
            const int w0 = px0 + t * 16 + n;
#pragma unroll
            for (int r = 0; r < 4; ++r)
                yp[(size_t)(mt * 16 + 4 * q + r) * 16384 + w0] = yacc[mt][t][r];
        }

    float sv[8], qv[8];
#pragma unroll
    for (int mt = 0; mt < 2; ++mt)
#pragma unroll
        for (int r = 0; r < 4; ++r) {
            float v0 = yacc[mt][0][r], v1 = yacc[mt][1][r];
            sv[mt * 4 + r] = v0 + v1;
            qv[mt * 4 + r] = v0 * v0 + v1 * v1;
        }
#pragma unroll
    for (int m = 1; m <= 8; m <<= 1)
#pragma unroll
        for (int i = 0; i < 8; ++i) {
            sv[i] += __shfl_xor(sv[i], m);
            qv[i] += __shfl_xor(qv[i], m);
        }
    if (n == 0) {
#pragma unroll
        for (int i = 0; i < 8; ++i) {
            stat_lds[wave][q][i]     = sv[i];
            stat_lds[wave][q][i + 8] = qv[i];
        }
    }
    __syncthreads();
    if (tid < 64) {
        int qq = tid >> 4, i = tid & 15;
        float acc = stat_lds[0][qq][i] + stat_lds[1][qq][i] +
                    stat_lds[2][qq][i] + stat_lds[3][qq][i];
        int kind = i >> 3, mt = (i >> 2) & 1, r = i & 3;
        int o = mt * 16 + 4 * qq + r;
        atomicAdd(&stats[(b * 32 + o) * 2 + kind], acc);
    }
}

// ---- normalize + transposed store via LDS tiles --------------------------
__global__ void inorm2(const float* __restrict__ ypart, const float* __restrict__ stats,
                       float* __restrict__ out)
{
    const int bid = blockIdx.x;                 // 2048 = 128 (b,o) x 16 tiles
    const int bo = bid >> 4, tile = bid & 15;
    const int h0 = (tile >> 2) * 32, w0 = (tile & 3) * 32;
    const float mean = stats[bo * 2] * (1.f / 16384.f);
    float var = stats[bo * 2 + 1] * (1.f / 16384.f) - mean * mean;
    const float rstd = rsqrtf(fmaxf(var, 0.f) + 1e-5f);

    const float* y0 = ypart + (size_t)bo * 16384;
    __shared__ float tilebuf[32][33];
    const int r = threadIdx.x >> 3, c4 = (threadIdx.x & 7) * 4;

    const size_t base = (size_t)(h0 + r) * 128 + w0 + c4;
    fx4 a = *(const fx4*)(y0 + base);
#pragma unroll
    for (int j = 0; j < 4; ++j)
        tilebuf[r][c4 + j] = (a[j] - mean) * rstd;
    __syncthreads();
    float* ob = out + (size_t)bo * 16384 + (size_t)(w0 + r) * 128 + h0 + c4;
    fx4 o4;
#pragma unroll
    for (int j = 0; j < 4; ++j) o4[j] = tilebuf[c4 + j][r];
    *(fx4*)ob = o4;
}

extern "C" void kernel_launch(void* const* d_in, const int* in_sizes, int n_in,
                              void* d_out, int out_size, void* d_ws, size_t ws_size,
                              hipStream_t stream)
{
    const float* x    = (const float*)d_in[0];
    const float* filt = (const float*)d_in[1];
    const float* w1   = (const float*)d_in[2];
    // d_in[3] = b1: cancels under instance norm, unused.
    float* out = (float*)d_out;
    char* ws = (char*)d_ws;

    unsigned short* Aw    = (unsigned short*)(ws + A_OFF);
    unsigned short* w1b   = (unsigned short*)(ws + W1B_OFF);
    float*          yp    = (float*)(ws + YP_OFF);
    float*          stats = (float*)(ws + ST_OFF);

    prep<<<177, 256, 0, stream>>>(filt, w1, Aw, w1b, stats);
    conv_mix<<<512, 256, 0, stream>>>(x, Aw, w1b, yp, stats);
    inorm2<<<2048, 256, 0, stream>>>(yp, stats, out);
}